// Round 1
// baseline (1921.171 us; speedup 1.0000x reference)
//
#include <hip/hip_runtime.h>
#include <float.h>
#include <math.h>

#define NN 50000      // batch nodes
#define EE 250000     // edges
#define BB 20000      // events
#define INV_SCALE 0.14142135623730950488f  // 1/sqrt(50)

// ---------------- K1: q,k,v,xs = memory[n_id] @ {Wq,Wk,Wv,Ws} + bias ----------------
__global__ __launch_bounds__(256) void k1_node_transform(
    const int* __restrict__ n_id, const float* __restrict__ memory,
    const float* __restrict__ Wq, const float* __restrict__ bq,
    const float* __restrict__ Wk, const float* __restrict__ bk,
    const float* __restrict__ Wv, const float* __restrict__ bv,
    const float* __restrict__ Ws, const float* __restrict__ bs,
    float* __restrict__ q, float* __restrict__ k,
    float* __restrict__ v, float* __restrict__ xs)
{
  __shared__ __align__(16) float x_tile[32 * 100];
  __shared__ __align__(16) float W_lds[100 * 100];   // transposed: [o][k]
  __shared__ int nid_s[32];
  const int t = threadIdx.x;
  const int node0 = blockIdx.x * 32;
  if (t < 32) {
    int n = node0 + t;
    nid_s[t] = (n < NN) ? n_id[n] : -1;
  }
  __syncthreads();
  for (int i = t; i < 3200; i += 256) {
    int n = i / 100, c = i - n * 100;
    int nn = nid_s[n];
    x_tile[n * 100 + c] = (nn >= 0) ? memory[(size_t)nn * 100 + c] : 0.f;
  }
  const int o = t & 127;
  const int oc = (o < 100) ? o : 0;
  const int g = t >> 7;
  const float* Wm[4] = {Wq, Wk, Wv, Ws};
  const float* bm[4] = {bq, bk, bv, bs};
  float* outm[4] = {q, k, v, xs};
  for (int m = 0; m < 4; ++m) {
    __syncthreads();
    const float* W = Wm[m];
    for (int i = t; i < 10000; i += 256) {
      int kk = i / 100, oo = i - kk * 100;
      W_lds[oo * 100 + kk] = W[i];
    }
    __syncthreads();
    float bias = (o < 100) ? bm[m][o] : 0.f;
    float* outp = outm[m];
    for (int chunk = 0; chunk < 2; ++chunk) {
      int nb = g * 16 + chunk * 8;
      float acc[8];
      #pragma unroll
      for (int r = 0; r < 8; ++r) acc[r] = bias;
      for (int k4 = 0; k4 < 100; k4 += 4) {
        float4 w4 = *reinterpret_cast<const float4*>(&W_lds[oc * 100 + k4]);
        #pragma unroll
        for (int r = 0; r < 8; ++r) {
          float4 x4 = *reinterpret_cast<const float4*>(&x_tile[(nb + r) * 100 + k4]);
          acc[r] += x4.x * w4.x + x4.y * w4.y + x4.z * w4.z + x4.w * w4.w;
        }
      }
      if (o < 100) {
        #pragma unroll
        for (int r = 0; r < 8; ++r) {
          int n = node0 + nb + r;
          if (n < NN) outp[(size_t)n * 100 + o] = acc[r];
        }
      }
    }
  }
}

// ---------------- K2: e_row = [cos(rel_t*wt+bt) || msg] @ We ; logits ; cnt ----------------
__global__ __launch_bounds__(512) void k2_edge(
    const int* __restrict__ ei, const int* __restrict__ e_id,
    const int* __restrict__ n_id,
    const float* __restrict__ msg_store, const float* __restrict__ t_store,
    const float* __restrict__ last_up,
    const float* __restrict__ wt, const float* __restrict__ bt,
    const float* __restrict__ We,
    const float* __restrict__ q, const float* __restrict__ kk,
    float* __restrict__ e_row, float* __restrict__ logits,
    int* __restrict__ cnt)
{
  __shared__ __align__(16) float We_t[100 * 200];   // [o][k]  80 KB
  __shared__ __align__(16) float attr[32 * 200];    // 25.6 KB
  __shared__ __align__(16) float e_tile[32 * 100];  // 12.8 KB
  __shared__ float rel_s[32];
  const int t = threadIdx.x;
  const int eb = blockIdx.x * 32;
  for (int i = t; i < 20000; i += 512) {
    int kv = i / 100, ov = i - kv * 100;
    We_t[ov * 200 + kv] = We[i];
  }
  if (t < 32) {
    int ed = eb + t;
    float rt = 0.f;
    if (ed < EE) {
      rt = last_up[n_id[ei[ed]]] - t_store[e_id[ed]];
      atomicAdd(&cnt[ei[EE + ed]], 1);
    }
    rel_s[t] = rt;
  }
  __syncthreads();
  for (int i = t; i < 6400; i += 512) {
    int el = i / 200, c = i - el * 200;
    int ed = eb + el;
    float val = 0.f;
    if (ed < EE) {
      if (c < 100) val = cosf(rel_s[el] * wt[c] + bt[c]);
      else         val = msg_store[(size_t)e_id[ed] * 100 + (c - 100)];
    }
    attr[el * 200 + c] = val;
  }
  __syncthreads();
  const int o = t & 127;
  const int oc = (o < 100) ? o : 0;
  const int g = t >> 7;
  float acc[8];
  #pragma unroll
  for (int r = 0; r < 8; ++r) acc[r] = 0.f;
  for (int k4 = 0; k4 < 200; k4 += 4) {
    float4 w4 = *reinterpret_cast<const float4*>(&We_t[oc * 200 + k4]);
    #pragma unroll
    for (int r = 0; r < 8; ++r) {
      float4 a4 = *reinterpret_cast<const float4*>(&attr[(g * 8 + r) * 200 + k4]);
      acc[r] += a4.x * w4.x + a4.y * w4.y + a4.z * w4.z + a4.w * w4.w;
    }
  }
  #pragma unroll
  for (int r = 0; r < 8; ++r) {
    int el = g * 8 + r;
    int ed = eb + el;
    if (o < 100) {
      e_tile[el * 100 + o] = acc[r];
      if (ed < EE) e_row[(size_t)ed * 100 + o] = acc[r];
    }
  }
  __syncthreads();
  // logits: 16 threads per edge, 8 lanes per head
  int el = t >> 4, sub = t & 15, h = sub >> 3, part = sub & 7;
  int ed = eb + el;
  float partial = 0.f;
  if (ed < EE) {
    int s_n = ei[ed], d_n = ei[EE + ed];
    const float* qr = q + (size_t)d_n * 100 + h * 50;
    const float* kr = kk + (size_t)s_n * 100 + h * 50;
    const float* er = &e_tile[el * 100 + h * 50];
    #pragma unroll
    for (int j = 0; j < 7; ++j) {
      int ol = part * 7 + j;
      if (ol < 50) partial += qr[ol] * (kr[ol] + er[ol]);
    }
  }
  partial += __shfl_xor(partial, 4);
  partial += __shfl_xor(partial, 2);
  partial += __shfl_xor(partial, 1);
  if (part == 0 && ed < EE) logits[(size_t)ed * 2 + h] = partial * INV_SCALE;
}

// ---------------- CSR build: scan + scatter ----------------
__global__ __launch_bounds__(1024) void s1_scan(const int* __restrict__ cnt,
                                                int* __restrict__ off, int* __restrict__ bsum)
{
  __shared__ int sdata[1024];
  int t = threadIdx.x, i = blockIdx.x * 1024 + t;
  int v = (i < NN) ? cnt[i] : 0;
  sdata[t] = v;
  __syncthreads();
  for (int s = 1; s < 1024; s <<= 1) {
    int x = (t >= s) ? sdata[t - s] : 0;
    __syncthreads();
    sdata[t] += x;
    __syncthreads();
  }
  if (i < NN) off[i] = sdata[t] - v;
  if (t == 1023) bsum[blockIdx.x] = sdata[1023];
}

__global__ void s2_scan(int* bsum, int* off, int nb)
{
  if (threadIdx.x == 0 && blockIdx.x == 0) {
    int run = 0;
    for (int b = 0; b < nb; ++b) { int tmp = bsum[b]; bsum[b] = run; run += tmp; }
    off[NN] = run;
  }
}

__global__ __launch_bounds__(1024) void s3_add(int* __restrict__ off, int* __restrict__ pos,
                                               const int* __restrict__ bsum)
{
  int t = threadIdx.x, i = blockIdx.x * 1024 + t;
  if (i < NN) {
    int o = off[i] + bsum[blockIdx.x];
    off[i] = o;
    pos[i] = o;
  }
}

__global__ __launch_bounds__(256) void k3_scatter(const int* __restrict__ ei,
                                                  int* __restrict__ pos, int* __restrict__ elist)
{
  int ed = blockIdx.x * 256 + threadIdx.x;
  if (ed < EE) {
    int p = atomicAdd(&pos[ei[EE + ed]], 1);
    elist[p] = ed;
  }
}

// ---------------- K4: per-dst segment softmax + weighted sum; z written in-place over xs ----------------
__global__ __launch_bounds__(256) void k4_attn_out(
    const int* __restrict__ ei, const int* __restrict__ off, const int* __restrict__ elist,
    const float* __restrict__ logits, const float* __restrict__ e_row,
    const float* __restrict__ v, float* __restrict__ xz)
{
  const int t = threadIdx.x;
  const int wave = t >> 6, lane = t & 63;
  const int d = blockIdx.x * 4 + wave;
  if (d >= NN) return;
  const int start = off[d], end = off[d + 1];
  const int deg = end - start;
  float m0 = -FLT_MAX, m1 = -FLT_MAX;
  for (int i = lane; i < deg; i += 64) {
    int ed = elist[start + i];
    m0 = fmaxf(m0, logits[(size_t)ed * 2]);
    m1 = fmaxf(m1, logits[(size_t)ed * 2 + 1]);
  }
  for (int s = 32; s; s >>= 1) { m0 = fmaxf(m0, __shfl_xor(m0, s)); m1 = fmaxf(m1, __shfl_xor(m1, s)); }
  float s0 = 0.f, s1 = 0.f;
  for (int i = lane; i < deg; i += 64) {
    int ed = elist[start + i];
    s0 += expf(logits[(size_t)ed * 2] - m0);
    s1 += expf(logits[(size_t)ed * 2 + 1] - m1);
  }
  for (int s = 32; s; s >>= 1) { s0 += __shfl_xor(s0, s); s1 += __shfl_xor(s1, s); }
  float inv0 = 1.f / (s0 + 1e-16f), inv1 = 1.f / (s1 + 1e-16f);
  const int f = lane;           // 0..63
  const int f2 = 64 + lane;     // 64..99 valid for lane<36
  float acc0 = xz[(size_t)d * 100 + f];
  float acc1 = (lane < 36) ? xz[(size_t)d * 100 + f2] : 0.f;
  for (int jj = start; jj < end; ++jj) {
    int ed = elist[jj];
    float a0 = expf(logits[(size_t)ed * 2] - m0) * inv0;
    float a1 = expf(logits[(size_t)ed * 2 + 1] - m1) * inv1;
    const float* vr = v + (size_t)ei[ed] * 100;
    const float* er = e_row + (size_t)ed * 100;
    acc0 += (vr[f] + er[f]) * (f < 50 ? a0 : a1);
    if (lane < 36) acc1 += (vr[f2] + er[f2]) * a1;
  }
  xz[(size_t)d * 100 + f] = acc0;
  if (lane < 36) xz[(size_t)d * 100 + f2] = acc1;
}

// ---------------- K5: link predictor ----------------
__global__ __launch_bounds__(256) void k5_pred(
    const int* __restrict__ srcv, const int* __restrict__ dstv, const int* __restrict__ negv,
    const float* __restrict__ z,
    const float* __restrict__ Wls, const float* __restrict__ bls,
    const float* __restrict__ Wld, const float* __restrict__ bld,
    const float* __restrict__ Wlf, const float* __restrict__ blf,
    float* __restrict__ out)
{
  __shared__ __align__(16) float Wls_t[100 * 100];
  __shared__ __align__(16) float Wld_t[100 * 100];
  __shared__ __align__(16) float rows[2][3][100];
  __shared__ float bb_s[100], wlf_s[100];
  __shared__ float red[4][2];
  const int t = threadIdx.x;
  for (int i = t; i < 10000; i += 256) {
    int kv = i / 100, ov = i - kv * 100;
    Wls_t[ov * 100 + kv] = Wls[i];
    Wld_t[ov * 100 + kv] = Wld[i];
  }
  if (t < 100) { bb_s[t] = bls[t] + bld[t]; wlf_s[t] = Wlf[t]; }
  const float blf0 = blf[0];
  const int half = t >> 7, l = t & 127;
  const int lc = (l < 100) ? l : 0;
  const int npairs = (BB + 1) / 2;
  for (int p = blockIdx.x; p < npairs; p += gridDim.x) {
    int ev = 2 * p + half;
    bool valid = ev < BB;
    __syncthreads();
    if (valid && l < 100) {
      rows[half][0][l] = z[(size_t)srcv[ev] * 100 + l];
      rows[half][1][l] = z[(size_t)dstv[ev] * 100 + l];
      rows[half][2][l] = z[(size_t)negv[ev] * 100 + l];
    }
    __syncthreads();
    float u = 0.f, d1 = 0.f, d2 = 0.f;
    for (int k4 = 0; k4 < 100; k4 += 4) {
      float4 wl = *reinterpret_cast<const float4*>(&Wls_t[lc * 100 + k4]);
      float4 wd = *reinterpret_cast<const float4*>(&Wld_t[lc * 100 + k4]);
      float4 a = *reinterpret_cast<const float4*>(&rows[half][0][k4]);
      float4 b = *reinterpret_cast<const float4*>(&rows[half][1][k4]);
      float4 c = *reinterpret_cast<const float4*>(&rows[half][2][k4]);
      u  += a.x * wl.x + a.y * wl.y + a.z * wl.z + a.w * wl.w;
      d1 += b.x * wd.x + b.y * wd.y + b.z * wd.z + b.w * wd.w;
      d2 += c.x * wd.x + c.y * wd.y + c.z * wd.z + c.w * wd.w;
    }
    float h1 = 0.f, h2 = 0.f;
    if (l < 100) {
      float bb = bb_s[l], wf = wlf_s[l];
      h1 = fmaxf(u + d1 + bb, 0.f) * wf;
      h2 = fmaxf(u + d2 + bb, 0.f) * wf;
    }
    for (int s = 32; s; s >>= 1) { h1 += __shfl_xor(h1, s); h2 += __shfl_xor(h2, s); }
    int w = t >> 6;
    if ((t & 63) == 0) { red[w][0] = h1; red[w][1] = h2; }
    __syncthreads();
    if (valid && l == 0) {
      out[ev]      = red[half * 2][0] + red[half * 2 + 1][0] + blf0;
      out[BB + ev] = red[half * 2][1] + red[half * 2 + 1][1] + blf0;
    }
  }
}

extern "C" void kernel_launch(void* const* d_in, const int* in_sizes, int n_in,
                              void* d_out, int out_size, void* d_ws, size_t ws_size,
                              hipStream_t stream)
{
  const int*   src    = (const int*)d_in[0];
  const int*   dst    = (const int*)d_in[1];
  const int*   neg    = (const int*)d_in[2];
  const int*   n_id   = (const int*)d_in[3];
  const int*   ei     = (const int*)d_in[4];
  const int*   e_id   = (const int*)d_in[5];
  const float* msg_st = (const float*)d_in[6];
  const float* t_st   = (const float*)d_in[7];
  const float* memory = (const float*)d_in[8];
  const float* lastup = (const float*)d_in[9];
  const float* wt = (const float*)d_in[10];
  const float* bt = (const float*)d_in[11];
  const float* Wq = (const float*)d_in[12]; const float* bq = (const float*)d_in[13];
  const float* Wk = (const float*)d_in[14]; const float* bk = (const float*)d_in[15];
  const float* Wv = (const float*)d_in[16]; const float* bv = (const float*)d_in[17];
  const float* We = (const float*)d_in[18];
  const float* Ws = (const float*)d_in[19]; const float* bs = (const float*)d_in[20];
  const float* Wls = (const float*)d_in[21]; const float* bls = (const float*)d_in[22];
  const float* Wld = (const float*)d_in[23]; const float* bld = (const float*)d_in[24];
  const float* Wlf = (const float*)d_in[25]; const float* blf = (const float*)d_in[26];
  float* out = (float*)d_out;

  char* ws = (char*)d_ws;
  size_t cur = 0;
  auto alloc = [&](size_t bytes) -> void* {
    void* p = ws + cur;
    cur += (bytes + 255) & ~size_t(255);
    return p;
  };
  float* q     = (float*)alloc((size_t)NN * 100 * 4);
  float* kk    = (float*)alloc((size_t)NN * 100 * 4);
  float* v     = (float*)alloc((size_t)NN * 100 * 4);
  float* xz    = (float*)alloc((size_t)NN * 100 * 4);   // xs, overwritten in-place with z
  float* e_row = (float*)alloc((size_t)EE * 100 * 4);
  float* logit = (float*)alloc((size_t)EE * 2 * 4);
  int*   cnt   = (int*)alloc((size_t)NN * 4);
  int*   off   = (int*)alloc((size_t)(NN + 1) * 4);
  int*   pos   = (int*)alloc((size_t)NN * 4);
  int*   bsum  = (int*)alloc(64 * 4);
  int*   elist = (int*)alloc((size_t)EE * 4);
  (void)ws_size; (void)in_sizes; (void)n_in; (void)out_size;

  hipMemsetAsync(cnt, 0, (size_t)NN * 4, stream);
  k1_node_transform<<<(NN + 31) / 32, 256, 0, stream>>>(
      n_id, memory, Wq, bq, Wk, bk, Wv, bv, Ws, bs, q, kk, v, xz);
  k2_edge<<<(EE + 31) / 32, 512, 0, stream>>>(
      ei, e_id, n_id, msg_st, t_st, lastup, wt, bt, We, q, kk, e_row, logit, cnt);
  int nb = (NN + 1023) / 1024;
  s1_scan<<<nb, 1024, 0, stream>>>(cnt, off, bsum);
  s2_scan<<<1, 64, 0, stream>>>(bsum, off, nb);
  s3_add<<<nb, 1024, 0, stream>>>(off, pos, bsum);
  k3_scatter<<<(EE + 255) / 256, 256, 0, stream>>>(ei, pos, elist);
  k4_attn_out<<<NN / 4, 256, 0, stream>>>(ei, off, elist, logit, e_row, v, xz);
  k5_pred<<<256, 256, 0, stream>>>(src, dst, neg, xz, Wls, bls, Wld, bld, Wlf, blf, out);
}